// Round 1
// baseline (116.281 us; speedup 1.0000x reference)
//
#include <hip/hip_runtime.h>
#include <hip/hip_fp16.h>

#define BATCH 32
#define TLEN  4096
#define CH    128      // C == F == 128
#define KW    3
#define DIL   8

typedef _Float16 f16x8 __attribute__((ext_vector_type(8)));
typedef float    f32x4 __attribute__((ext_vector_type(4)));

// ---------------------------------------------------------------------------
// Prep: Wt[j][f][c] = (f16) W[c][j][f]   for both layers' kernels.
// W is (C, K, F) row-major: W[c*KW*CH + j*CH + f].
// ---------------------------------------------------------------------------
__global__ void prep_weights_kernel(const float* __restrict__ W1,
                                    const float* __restrict__ W2,
                                    _Float16* __restrict__ Wt1,
                                    _Float16* __restrict__ Wt2) {
    const int total = KW * CH * CH;
    int idx = blockIdx.x * 256 + threadIdx.x;
    if (idx >= 2 * total) return;
    const float* W  = (idx < total) ? W1 : W2;
    _Float16*    Wt = (idx < total) ? Wt1 : Wt2;
    int r = idx % total;
    int j = r / (CH * CH);
    int f = (r / CH) % CH;
    int c = r % CH;
    Wt[j * CH * CH + f * CH + c] = (_Float16)W[c * (KW * CH) + j * CH + f];
}

// ---------------------------------------------------------------------------
// One "deconv" layer as a GEMM:
//   acc[t][f] = sum_{j,c} in[b, t + (2-j)*DIL, c] * Wt[j][f][c]
//   layer1 (!RESIDUAL): out = f16( relu(acc + nv*128*bias) )
//   layer2 ( RESIDUAL): out = f32( relu( relu(acc + nv*128*bias) + x ) )
// Tile: BM=128 (t), BN=128 (=F), BK=32. 256 threads = 4 waves, each 64x64.
// ---------------------------------------------------------------------------
template<bool IN_F16, bool RESIDUAL>
__global__ __launch_bounds__(256)
void deconv_gemm_kernel(const void* __restrict__ inp,       // f32 x or f16 h, [B][T][CH]
                        const _Float16* __restrict__ Wt,    // [KW][CH(f)][CH(c)]
                        const float* __restrict__ bias,     // [CH]
                        const float* __restrict__ resid,    // x f32 (layer2 only)
                        void* __restrict__ outp)            // f16 h or f32 out
{
    // +8 f16 pad per row: 80B stride -> <=2-way LDS bank aliasing (free)
    __shared__ __align__(16) _Float16 As[128][40];
    __shared__ __align__(16) _Float16 Bs[128][40];

    const int tid  = threadIdx.x;
    const int lane = tid & 63;
    const int wid  = tid >> 6;
    const int mr   = (wid >> 1) * 64;   // wave row base
    const int nc   = (wid & 1) * 64;    // wave col base
    const int l15  = lane & 15;
    const int kg   = lane >> 4;         // k-group 0..3

    const int mt = blockIdx.x;
    const int b  = mt >> 5;             // TLEN/128 = 32 tiles per batch
    const int t0 = (mt & 31) << 7;

    f32x4 acc[4][4];
#pragma unroll
    for (int m = 0; m < 4; ++m)
#pragma unroll
        for (int n = 0; n < 4; ++n)
            acc[m][n] = (f32x4){0.f, 0.f, 0.f, 0.f};

    const int srow  = tid >> 1;         // staging row 0..127
    const int shalf = tid & 1;          // which 16-wide half of the 32-wide K slice

    for (int ks = 0; ks < 12; ++ks) {
        const int j  = ks >> 2;         // tap index 0..2 (4 K-steps per tap)
        const int c0 = (ks & 3) << 5;   // channel base within tap

        // ---- stage A tile: As[r][kk] = in[b, t0+r+(2-j)*8, c0+kk]
        {
            const int t = t0 + srow + (2 - j) * DIL;
            _Float16* dst = &As[srow][shalf * 16];
            if (t < TLEN) {
                if constexpr (!IN_F16) {
                    const float* xp = (const float*)inp
                        + ((size_t)b * TLEN + t) * CH + c0 + shalf * 16;
                    f32x4 v0 = *(const f32x4*)(xp + 0);
                    f32x4 v1 = *(const f32x4*)(xp + 4);
                    f32x4 v2 = *(const f32x4*)(xp + 8);
                    f32x4 v3 = *(const f32x4*)(xp + 12);
                    f16x8 o0, o1;
                    o0[0]=(_Float16)v0[0]; o0[1]=(_Float16)v0[1];
                    o0[2]=(_Float16)v0[2]; o0[3]=(_Float16)v0[3];
                    o0[4]=(_Float16)v1[0]; o0[5]=(_Float16)v1[1];
                    o0[6]=(_Float16)v1[2]; o0[7]=(_Float16)v1[3];
                    o1[0]=(_Float16)v2[0]; o1[1]=(_Float16)v2[1];
                    o1[2]=(_Float16)v2[2]; o1[3]=(_Float16)v2[3];
                    o1[4]=(_Float16)v3[0]; o1[5]=(_Float16)v3[1];
                    o1[6]=(_Float16)v3[2]; o1[7]=(_Float16)v3[3];
                    *(f16x8*)(dst + 0) = o0;
                    *(f16x8*)(dst + 8) = o1;
                } else {
                    const _Float16* hp = (const _Float16*)inp
                        + ((size_t)b * TLEN + t) * CH + c0 + shalf * 16;
                    *(f16x8*)(dst + 0) = *(const f16x8*)(hp + 0);
                    *(f16x8*)(dst + 8) = *(const f16x8*)(hp + 8);
                }
            } else {
                f16x8 z = {};
                *(f16x8*)(dst + 0) = z;
                *(f16x8*)(dst + 8) = z;
            }
        }

        // ---- stage B tile: Bs[f][kk] = Wt[j][f][c0+kk]  (already transposed)
        {
            const _Float16* wp = Wt + (size_t)j * (CH * CH) + srow * CH + c0 + shalf * 16;
            _Float16* dst = &Bs[srow][shalf * 16];
            *(f16x8*)(dst + 0) = *(const f16x8*)(wp + 0);
            *(f16x8*)(dst + 8) = *(const f16x8*)(wp + 8);
        }

        __syncthreads();

        // ---- fragments + MFMA
        f16x8 a[4], bb[4];
#pragma unroll
        for (int m = 0; m < 4; ++m)
            a[m] = *(const f16x8*)&As[mr + m * 16 + l15][kg * 8];
#pragma unroll
        for (int n = 0; n < 4; ++n)
            bb[n] = *(const f16x8*)&Bs[nc + n * 16 + l15][kg * 8];
#pragma unroll
        for (int m = 0; m < 4; ++m)
#pragma unroll
            for (int n = 0; n < 4; ++n)
                acc[m][n] = __builtin_amdgcn_mfma_f32_16x16x32_f16(a[m], bb[n], acc[m][n], 0, 0, 0);

        __syncthreads();
    }

    // ---- epilogue: D mapping col=lane&15, row=(lane>>4)*4+i (m89-verified)
#pragma unroll
    for (int n = 0; n < 4; ++n) {
        const int f = nc + n * 16 + l15;
        const float bv = 128.0f * bias[f];
#pragma unroll
        for (int m = 0; m < 4; ++m) {
#pragma unroll
            for (int i = 0; i < 4; ++i) {
                const int row = mr + m * 16 + kg * 4 + i;
                const int t = t0 + row;
                const int nv = 1 + (t < TLEN - DIL) + (t < TLEN - 2 * DIL);
                float v = acc[m][n][i] + (float)nv * bv;
                v = fmaxf(v, 0.0f);
                const size_t gi = ((size_t)b * TLEN + t) * CH + f;
                if constexpr (RESIDUAL) {
                    v = fmaxf(v + resid[gi], 0.0f);
                    ((float*)outp)[gi] = v;
                } else {
                    ((_Float16*)outp)[gi] = (_Float16)v;
                }
            }
        }
    }
}

// ---------------------------------------------------------------------------
extern "C" void kernel_launch(void* const* d_in, const int* in_sizes, int n_in,
                              void* d_out, int out_size, void* d_ws, size_t ws_size,
                              hipStream_t stream) {
    const float* x  = (const float*)d_in[0];
    const float* W1 = (const float*)d_in[1];
    const float* b1 = (const float*)d_in[2];
    const float* W2 = (const float*)d_in[3];
    const float* b2 = (const float*)d_in[4];
    float* out = (float*)d_out;

    // workspace layout: h (B*T*CH f16, 32MB) | Wt1 (3*128*128 f16) | Wt2
    _Float16* h   = (_Float16*)d_ws;
    _Float16* Wt1 = h + (size_t)BATCH * TLEN * CH;
    _Float16* Wt2 = Wt1 + KW * CH * CH;

    const int grid = BATCH * (TLEN / 128);   // 1024 blocks

    prep_weights_kernel<<<(2 * KW * CH * CH + 255) / 256, 256, 0, stream>>>(W1, W2, Wt1, Wt2);
    deconv_gemm_kernel<false, false><<<grid, 256, 0, stream>>>(x, Wt1, b1, nullptr, h);
    deconv_gemm_kernel<true,  true ><<<grid, 256, 0, stream>>>(h, Wt2, b2, x, out);
}

// Round 2
// 83.029 us; speedup vs baseline: 1.4005x; 1.4005x over previous
//
#include <hip/hip_runtime.h>
#include <hip/hip_fp16.h>

#define BATCH 32
#define TLEN  4096
#define CH    128      // C == F == 128
#define KW    3
#define DIL   8

#define BM    64                 // output rows per block
#define HROWS (BM + 2 * DIL)     // 80  h rows needed
#define XROWS (BM + 4 * DIL)     // 96  x rows needed
#define LDSC  132                // padded row length (f16), 264B stride

typedef _Float16 f16x8 __attribute__((ext_vector_type(8)));
typedef float    f32x4 __attribute__((ext_vector_type(4)));

// ---------------------------------------------------------------------------
// Prep: Wt[j][f][c] = (f16) W[c][j][f]   for both layers' kernels.
// W is (C, K, F) row-major: W[c*KW*CH + j*CH + f].
// ---------------------------------------------------------------------------
__global__ void prep_weights_kernel(const float* __restrict__ W1,
                                    const float* __restrict__ W2,
                                    _Float16* __restrict__ Wt1,
                                    _Float16* __restrict__ Wt2) {
    const int total = KW * CH * CH;
    int idx = blockIdx.x * 256 + threadIdx.x;
    if (idx >= 2 * total) return;
    const float* W  = (idx < total) ? W1 : W2;
    _Float16*    Wt = (idx < total) ? Wt1 : Wt2;
    int r = idx % total;
    int j = r / (CH * CH);
    int f = (r / CH) % CH;
    int c = r % CH;
    Wt[j * CH * CH + f * CH + c] = (_Float16)W[c * (KW * CH) + j * CH + f];
}

// ---------------------------------------------------------------------------
// Fused TemporalDeConvBlock:
//   h[u,f]  = relu( sum_{j,c} x[u+(2-j)*D, c] W1[c,j,f] + nv(u)*128*b1[f] ),  u>=T -> 0
//   o[t,f]  = relu( relu( sum_{j,c} h[t+(2-j)*D, c] W2[c,j,f] + nv(t)*128*b2[f] ) + x[t,f] )
// Per block: stage x rows t0..t0+95 once (f16), GEMM1 -> hs in LDS,
// GEMM2 -> epilogue with residual from the staged x window.
// 256 threads = 4 waves, n-split: wave w owns cols [32w, 32w+32).
// ---------------------------------------------------------------------------
__global__ __launch_bounds__(256, 3)
void fused_deconv_kernel(const float* __restrict__ x,
                         const _Float16* __restrict__ Wt1,
                         const float* __restrict__ bias1,
                         const _Float16* __restrict__ Wt2,
                         const float* __restrict__ bias2,
                         float* __restrict__ out)
{
    __shared__ __align__(16) _Float16 xs[XROWS][LDSC];   // 96*132*2 = 25344 B
    __shared__ __align__(16) _Float16 hs[HROWS][LDSC];   // 80*132*2 = 21120 B

    const int tid  = threadIdx.x;
    const int lane = tid & 63;
    const int wid  = tid >> 6;
    const int l15  = lane & 15;
    const int kg   = lane >> 4;        // 0..3
    const int nc   = wid << 5;         // wave column base: 0,32,64,96

    const int bt = blockIdx.x;
    const int b  = bt >> 6;            // TLEN/BM = 64 tiles per batch
    const int t0 = (bt & 63) << 6;

    // ---- stage x window (f32 -> f16), rows t0..t0+XROWS-1, zero past TLEN
    for (int i = tid; i < XROWS * 16; i += 256) {
        const int row = i >> 4;
        const int c8  = (i & 15) << 3;
        const int t   = t0 + row;
        f16x8 o;
        if (t < TLEN) {
            const float* xp = x + ((size_t)b * TLEN + t) * CH + c8;
            f32x4 v0 = *(const f32x4*)(xp + 0);
            f32x4 v1 = *(const f32x4*)(xp + 4);
            o[0] = (_Float16)v0[0]; o[1] = (_Float16)v0[1];
            o[2] = (_Float16)v0[2]; o[3] = (_Float16)v0[3];
            o[4] = (_Float16)v1[0]; o[5] = (_Float16)v1[1];
            o[6] = (_Float16)v1[2]; o[7] = (_Float16)v1[3];
        } else {
            o = (f16x8){};
        }
        *(f16x8*)&xs[row][c8] = o;
    }

    // per-wave bias (col f = nc + n*16 + l15)
    const float bv1_0 = 128.0f * bias1[nc + l15];
    const float bv1_1 = 128.0f * bias1[nc + 16 + l15];
    const float bv2_0 = 128.0f * bias2[nc + l15];
    const float bv2_1 = 128.0f * bias2[nc + 16 + l15];

    __syncthreads();

    // ---- GEMM1: h window rows 0..HROWS-1, cols [nc, nc+32)
    f32x4 acc1[5][2];
#pragma unroll
    for (int m = 0; m < 5; ++m) {
        acc1[m][0] = (f32x4){0.f, 0.f, 0.f, 0.f};
        acc1[m][1] = (f32x4){0.f, 0.f, 0.f, 0.f};
    }
#pragma unroll
    for (int ks = 0; ks < 12; ++ks) {
        const int j     = ks >> 2;
        const int c0    = (ks & 3) << 5;
        const int shift = (2 - j) * DIL;
        const _Float16* wb = Wt1 + (size_t)j * (CH * CH) + c0 + kg * 8;
        f16x8 bf0 = *(const f16x8*)(wb + (nc + l15) * CH);
        f16x8 bf1 = *(const f16x8*)(wb + (nc + 16 + l15) * CH);
#pragma unroll
        for (int m = 0; m < 5; ++m) {
            f16x8 af = *(const f16x8*)&xs[m * 16 + shift + l15][c0 + kg * 8];
            acc1[m][0] = __builtin_amdgcn_mfma_f32_16x16x32_f16(af, bf0, acc1[m][0], 0, 0, 0);
            acc1[m][1] = __builtin_amdgcn_mfma_f32_16x16x32_f16(af, bf1, acc1[m][1], 0, 0, 0);
        }
    }

    // ---- store h window to LDS (relu + bias; rows past TLEN are zero)
#pragma unroll
    for (int m = 0; m < 5; ++m) {
#pragma unroll
        for (int n = 0; n < 2; ++n) {
            const float bv = (n == 0) ? bv1_0 : bv1_1;
            const int f = nc + n * 16 + l15;
#pragma unroll
            for (int i = 0; i < 4; ++i) {
                const int r = m * 16 + kg * 4 + i;
                const int u = t0 + r;
                const int nv = 1 + (u < TLEN - DIL) + (u < TLEN - 2 * DIL);
                float v = acc1[m][n][i] + (float)nv * bv;
                v = fmaxf(v, 0.0f);
                hs[r][f] = (u < TLEN) ? (_Float16)v : (_Float16)0.0f;
            }
        }
    }
    __syncthreads();

    // ---- GEMM2: out rows 0..BM-1, cols [nc, nc+32)
    f32x4 acc2[4][2];
#pragma unroll
    for (int m = 0; m < 4; ++m) {
        acc2[m][0] = (f32x4){0.f, 0.f, 0.f, 0.f};
        acc2[m][1] = (f32x4){0.f, 0.f, 0.f, 0.f};
    }
#pragma unroll
    for (int ks = 0; ks < 12; ++ks) {
        const int j     = ks >> 2;
        const int c0    = (ks & 3) << 5;
        const int shift = (2 - j) * DIL;
        const _Float16* wb = Wt2 + (size_t)j * (CH * CH) + c0 + kg * 8;
        f16x8 bf0 = *(const f16x8*)(wb + (nc + l15) * CH);
        f16x8 bf1 = *(const f16x8*)(wb + (nc + 16 + l15) * CH);
#pragma unroll
        for (int m = 0; m < 4; ++m) {
            f16x8 af = *(const f16x8*)&hs[m * 16 + shift + l15][c0 + kg * 8];
            acc2[m][0] = __builtin_amdgcn_mfma_f32_16x16x32_f16(af, bf0, acc2[m][0], 0, 0, 0);
            acc2[m][1] = __builtin_amdgcn_mfma_f32_16x16x32_f16(af, bf1, acc2[m][1], 0, 0, 0);
        }
    }

    // ---- epilogue: bias2 + relu, + residual (from staged f16 x), relu, store f32
#pragma unroll
    for (int m = 0; m < 4; ++m) {
#pragma unroll
        for (int n = 0; n < 2; ++n) {
            const float bv = (n == 0) ? bv2_0 : bv2_1;
            const int f = nc + n * 16 + l15;
#pragma unroll
            for (int i = 0; i < 4; ++i) {
                const int r = m * 16 + kg * 4 + i;
                const int t = t0 + r;
                const int nv = 1 + (t < TLEN - DIL) + (t < TLEN - 2 * DIL);
                float v = acc2[m][n][i] + (float)nv * bv;
                v = fmaxf(v, 0.0f);
                v = v + (float)xs[r][f];
                v = fmaxf(v, 0.0f);
                out[((size_t)b * TLEN + t) * CH + f] = v;
            }
        }
    }
}

// ---------------------------------------------------------------------------
extern "C" void kernel_launch(void* const* d_in, const int* in_sizes, int n_in,
                              void* d_out, int out_size, void* d_ws, size_t ws_size,
                              hipStream_t stream) {
    const float* x  = (const float*)d_in[0];
    const float* W1 = (const float*)d_in[1];
    const float* b1 = (const float*)d_in[2];
    const float* W2 = (const float*)d_in[3];
    const float* b2 = (const float*)d_in[4];
    float* out = (float*)d_out;

    // workspace: Wt1 (3*128*128 f16) | Wt2
    _Float16* Wt1 = (_Float16*)d_ws;
    _Float16* Wt2 = Wt1 + KW * CH * CH;

    prep_weights_kernel<<<(2 * KW * CH * CH + 255) / 256, 256, 0, stream>>>(W1, W2, Wt1, Wt2);

    const int grid = BATCH * (TLEN / BM);   // 2048 blocks
    fused_deconv_kernel<<<grid, 256, 0, stream>>>(x, Wt1, b1, Wt2, b2, out);
}